// Round 12
// baseline (25.274 us; speedup 1.0000x reference)
//
#include <hip/hip_runtime.h>

#define NT 1024
#define NW 16        // waves per block
#define NH 4         // sub-histograms
#define NBOX 4096
#define NPT 4        // scores per thread
#define MAXDET 100
#define KSEL 192     // top-K selection target (>= 100 + NMS-suppressed margin)
#define CAP 256      // candidate capacity (4-thread rank requires C <= 256)

typedef unsigned long long u64;
typedef unsigned int u32;

__device__ __forceinline__ float iou_xyxy(float4 a, float4 c) {
  float aa = fmaxf(a.z - a.x, 0.f) * fmaxf(a.w - a.y, 0.f);
  float ca = fmaxf(c.z - c.x, 0.f) * fmaxf(c.w - c.y, 0.f);
  float w = fmaxf(fminf(a.z, c.z) - fmaxf(a.x, c.x), 0.f);
  float h = fmaxf(fminf(a.w, c.w) - fmaxf(a.y, c.y), 0.f);
  float inter = w * h;
  return inter / fmaxf(aa + ca - inter, 1e-9f);
}

__device__ __forceinline__ u64 wave_or64(u64 v) {
#pragma unroll
  for (int d = 1; d < 64; d <<= 1) v |= __shfl_xor(v, d);
  return v;
}

// Exact greedy over 64 slots: rows_mine = suppression row of element `lane`.
__device__ __forceinline__ u64 serial_greedy(u64 rows_mine, u64 removed) {
  u64 keep = 0ull;
  for (int ii = 0; ii < 64; ++ii) {
    u64 row = __shfl(rows_mine, ii);
    if (!((removed >> ii) & 1ull)) { keep |= 1ull << ii; removed |= row; }
  }
  return keep;
}

// 128-wide chunked greedy NMS over sorted (descending) keys.
// LDSBOX: boxes are pre-staged in rank order in cbst; else scattered global bx.
template <bool LDSBOX>
__device__ void run_nms128(const u64* keys, int len, const float4* __restrict__ bx,
                           const float4* cbst,
                           float4* chbox, float4* chcw, u64* srowLo, u64* srowHi,
                           u64* crossM, u64* keptkey, float4* keptxy, float4* keptcw,
                           int* p_kept, int tid) {
  const int lane = tid & 63;
  for (int base = 0; base < len; base += 128) {
    if (*p_kept >= MAXDET) break;  // uniform (written before a barrier)
    const int L = min(128, len - base);
    if (tid < 128) {  // ---- stage 128 boxes in one parallel round ----
      if (tid < 2) crossM[tid] = 0ull;
      float4 bb = make_float4(0.f, 0.f, 0.f, 0.f);
      float4 c = make_float4(0.f, 0.f, 0.f, 0.f);
      if (tid < L) {
        if (LDSBOX) {
          c = cbst[base + tid];  // contiguous: cbst is in rank order
        } else {
          u64 k = keys[base + tid];
          int orig = NBOX - 1 - (int)(k & 0xFFFFFFFFull);
          c = bx[orig];
        }
        bb = make_float4(c.x - 0.5f * c.z, c.y - 0.5f * c.w,
                         c.x + 0.5f * c.z, c.y + 0.5f * c.w);
      }
      chbox[tid] = bb;
      chcw[tid] = c;
      srowLo[tid] = 0ull;
      srowHi[tid] = 0ull;
    }
    __syncthreads();
    const int kept0 = *p_kept;
    {  // ---- pair tests: 128 rows x 8 slices ----
      int i = tid & 127, slice = tid >> 7;
      if (i < L) {
        float4 a = chbox[i];
        bool hit = false;
        for (int k0 = slice; k0 < kept0 && !hit; k0 += 8)
          if (iou_xyxy(a, keptxy[k0]) > 0.7f) hit = true;
        if (hit) atomicOr(&crossM[i >> 6], 1ull << (i & 63));
        u64 blo = 0ull, bhi = 0ull;
        for (int j = i + 1 + slice; j < L; j += 8)
          if (iou_xyxy(a, chbox[j]) > 0.7f) {
            if (j < 64) blo |= 1ull << j; else bhi |= 1ull << (j - 64);
          }
        if (blo) atomicOr(&srowLo[i], blo);
        if (bhi) atomicOr(&srowHi[i], bhi);
      }
    }
    __syncthreads();
    if (tid < 64) {  // ---- two-half greedy resolution, wave 0 ----
      u64 remL = crossM[0], remH = crossM[1];
      if (L < 64) remL |= ~((1ull << L) - 1ull);
      if (L <= 64) remH = ~0ull;
      else if (L < 128) remH |= ~((1ull << (L - 64)) - 1ull);
      u64 rAlo = srowLo[lane], rAhi = srowHi[lane];  // row of element lane
      u64 rBhi = srowHi[64 + lane];                  // row of element 64+lane
      // half 1
      u64 K1 = ~remL;
      u64 c1 = wave_or64(((K1 >> lane) & 1ull) ? (rAlo & K1) : 0ull);
      u64 keep1 = (c1 == 0ull) ? K1 : serial_greedy(rAlo, remL);
      // cross-suppression from half-1 keepers into half 2
      u64 remH2 = remH | wave_or64(((keep1 >> lane) & 1ull) ? rAhi : 0ull);
      // half 2
      u64 K2 = ~remH2;
      u64 c2 = wave_or64(((K2 >> lane) & 1ull) ? (rBhi & K2) : 0ull);
      u64 keep2 = (c2 == 0ull) ? K2 : serial_greedy(rBhi, remH2);
      // append
      int cnt1 = (int)__popcll(keep1);
      u64 below = (1ull << lane) - 1ull;
      if ((keep1 >> lane) & 1ull) {
        int pos = kept0 + (int)__popcll(keep1 & below);
        if (pos < MAXDET) {
          keptkey[pos] = keys[base + lane];
          keptxy[pos] = chbox[lane];
          keptcw[pos] = chcw[lane];
        }
      }
      if ((keep2 >> lane) & 1ull) {
        int pos = kept0 + cnt1 + (int)__popcll(keep2 & below);
        if (pos < MAXDET) {
          keptkey[pos] = keys[base + 64 + lane];
          keptxy[pos] = chbox[64 + lane];
          keptcw[pos] = chcw[64 + lane];
        }
      }
      if (lane == 0)
        *p_kept = min(MAXDET, kept0 + cnt1 + (int)__popcll(keep2));
    }
    __syncthreads();
  }
}

__global__ __launch_bounds__(NT) void postproc_kernel(
    const float* __restrict__ boxes,   // [B, NBOX, 4] cxcywh
    const float* __restrict__ scores,  // [B, NBOX]
    float* __restrict__ out,           // [B*MAXDET*5] packed, then [B] num
    int B) {
  const int b = blockIdx.x;
  const int tid = threadIdx.x, wid = tid >> 6, lane = tid & 63;

  __shared__ u32 hist[NH][256];    // 4KB sub-histograms (zeroed at entry)
  __shared__ u64 cand[CAP];        // compaction order
  __shared__ u64 sortedCand[CAP];  // rank order (descending)
  __shared__ float4 cbst[CAP];     // rank order -> cxcywh box
  __shared__ u64 skey[NBOX];       // 32KB, fallback full sort only
  __shared__ float4 chbox[128];    // chunk xyxy
  __shared__ float4 chcw[128];     // chunk cxcywh
  __shared__ u64 srowLo[128], srowHi[128];
  __shared__ u64 crossM[2];
  __shared__ float4 keptxy[MAXDET];
  __shared__ float4 keptcw[MAXDET];
  __shared__ u64 keptkey[MAXDET];
  __shared__ int s_M, s_C, s_kept, s_byte, s_above, s_bcnt;
  __shared__ int s_minP, s_maxP;

  const float* sc = scores + (size_t)b * NBOX;
  const float4* bx = (const float4*)boxes + (size_t)b * NBOX;

  if (tid == 0) {
    s_C = 0; s_kept = 0;
    s_byte = 0; s_above = 0; s_bcnt = -1;  // -1 = no crossing found
    s_minP = 0x7FFFFFFF; s_maxP = -1;
  }
  ((u32*)hist)[tid] = 0u;  // NT == NH*256: full zero

  // ---- Phase 1: load scores, build keys, histogram + exponent range ----
  u64 key[NPT];
  {
    const int t4 = tid * NPT;
    float4 f0 = *(const float4*)(sc + t4);  // issued; latency overlaps barrier
    __syncthreads();                        // B1: hist zero + s_* init visible
    float xs[NPT] = {f0.x, f0.y, f0.z, f0.w};
    int pmin = 0x7FFFFFFF, pmax = -1;
#pragma unroll
    for (int q = 0; q < NPT; ++q) {
      float x = xs[q];
      bool valid = (x > 0.5f);
      u32 bits = __float_as_uint(x);
      key[q] = valid ? (((u64)bits << 32) | (u64)(u32)(NBOX - 1 - (t4 + q))) : 0ull;
      if (valid) {
        int p = (int)(bits >> 23);
        pmin = min(pmin, p); pmax = max(pmax, p);
        atomicAdd(&hist[wid >> 2][(bits >> 15) & 255u], 1u);  // mantissa[22:15]
      }
    }
#pragma unroll
    for (int d = 1; d < 64; d <<= 1) {
      pmin = min(pmin, __shfl_xor(pmin, d));
      pmax = max(pmax, __shfl_xor(pmax, d));
    }
    if (lane == 0) {
      atomicMin(&s_minP, pmin);
      atomicMax(&s_maxP, pmax);
    }
  }
  __syncthreads();  // B2: hist + minP/maxP complete

  // ---- Phase 2: wave-0 suffix scan -> M, KSEL threshold crossing ----
  if (tid < 64) {
    int cc[4];
#pragma unroll
    for (int qq = 0; qq < 4; ++qq) {
      int bin = tid * 4 + qq;
      cc[qq] = (int)(hist[0][bin] + hist[1][bin] + hist[2][bin] + hist[3][bin]);
    }
    int tot = cc[0] + cc[1] + cc[2] + cc[3];
    int suf = tot;
#pragma unroll
    for (int d = 1; d < 64; d <<= 1) {
      int o = __shfl_down(suf, d);
      if (tid + d < 64) suf += o;
    }
    if (tid == 0) s_M = suf;  // total valid count
    if (suf - tot < KSEL && suf >= KSEL) {  // unique crossing lane
      int cum = suf - tot;
      for (int qq = 3; qq >= 0; --qq) {
        if (cum + cc[qq] >= KSEL) { s_byte = tid * 4 + qq; s_above = cum; s_bcnt = cc[qq]; break; }
        cum += cc[qq];
      }
    }
  }
  __syncthreads();  // B3
  const int M = s_M;
  const bool uniformP = (s_minP == s_maxP);  // all valid share sign+exp+mant[22:23]? (top 9 bits)
  bool fullpath = false, usehist = false;
  u32 thr = (u32)s_byte;
  if (M > CAP) {
    if (uniformP && s_bcnt >= 0) {
      usehist = true;
      if (s_above + s_bcnt > CAP) fullpath = true;  // fat bucket: exact fallback
    } else {
      fullpath = true;
    }
  }

  // ---- Phase 3: compact candidates (wave-aggregated atomics); C <= CAP exact ----
  if (!fullpath) {
#pragma unroll
    for (int q = 0; q < NPT; ++q) {
      bool take = key[q] && (!usehist || (((u32)(key[q] >> 47) & 255u) >= thr));
      u64 bal = __ballot(take);
      if (bal) {
        int leader = __ffsll((unsigned long long)bal) - 1;
        int basep = 0;
        if (lane == leader) basep = atomicAdd(&s_C, (int)__popcll(bal));
        basep = __shfl(basep, leader);
        if (take) {
          int pos = basep + (int)__popcll(bal & ((1ull << lane) - 1ull));
          cand[pos] = key[q];
        }
      }
    }
  }
  __syncthreads();  // B4
  const int C = s_C;

  // ---- Phase 4: gather+rank (4 threads/cand; gather thread == writer) + NMS ----
  if (!fullpath && C > 0) {
    const int i = tid >> 2, sl = tid & 3;
    u64 ki = 0ull;
    float4 gbox;
    const bool own = (sl == 0) && (i < C);
    if (i < C) ki = cand[i];  // LDS broadcast across the quad
    if (own) {                // issue scattered gather early; hides under rank
      int orig = NBOX - 1 - (int)(ki & 0xFFFFFFFFull);
      gbox = bx[orig];
    }
    int cnt = 0;
    if (i < C)
      for (int j = sl; j < C; j += 4) cnt += (cand[j] > ki) ? 1 : 0;
    cnt += __shfl_xor(cnt, 1);  // quad lanes share the same candidate
    cnt += __shfl_xor(cnt, 2);
    if (own) { sortedCand[cnt] = ki; cbst[cnt] = gbox; }  // boxes in rank order
    __syncthreads();  // B5
    run_nms128<true>(sortedCand, C, bx, cbst, chbox, chcw,
                     srowLo, srowHi, crossM, keptkey, keptxy, keptcw, &s_kept, tid);
  }

  // ---- Phase 5: fully-general fallback (pathological inputs only) ----
  const int kept1 = s_kept;
  const bool need_full = fullpath || (kept1 < MAXDET && usehist && C < M);
  __syncthreads();
  if (need_full) {
    if (tid == 0) s_kept = 0;
#pragma unroll
    for (int q = 0; q < NPT; ++q) {
      int n = tid * NPT + q;
      skey[n] = key[q] ? key[q] : (u64)(u32)(NBOX - 1 - n);
    }
    __syncthreads();
    for (int k = 2; k <= NBOX; k <<= 1)
      for (int j = k >> 1; j > 0; j >>= 1) {
#pragma clang loop unroll(disable)
        for (int t = tid; t < NBOX; t += NT) {
          int ixj = t ^ j;
          if (ixj > t) {
            u64 a = skey[t], c2 = skey[ixj];
            bool up = (t & k) != 0;
            if (up ? (a > c2) : (a < c2)) { skey[t] = c2; skey[ixj] = a; }
          }
        }
        __syncthreads();
      }
    run_nms128<false>(skey, M, bx, cbst, chbox, chcw,
                      srowLo, srowHi, crossM, keptkey, keptxy, keptcw, &s_kept, tid);
  }

  // ---- Phase 6: outputs (all from LDS; coalesced stores) ----
  const int nk = s_kept;
  if (tid < MAXDET) {
    float v0 = 0.f, v1 = 0.f, v2 = 0.f, v3 = 0.f, v4 = 0.f;
    if (tid < nk) {
      float4 bb = keptcw[tid];  // original cxcywh (staged during NMS)
      v0 = bb.x; v1 = bb.y; v2 = bb.z; v3 = bb.w;
      v4 = __uint_as_float((u32)(keptkey[tid] >> 32));
    }
    float* o = out + ((size_t)b * MAXDET + tid) * 5;
    o[0] = v0; o[1] = v1; o[2] = v2; o[3] = v3; o[4] = v4;
  }
  if (tid == 0) out[(size_t)B * MAXDET * 5 + b] = (float)nk;
}

extern "C" void kernel_launch(void* const* d_in, const int* in_sizes, int n_in,
                              void* d_out, int out_size, void* d_ws, size_t ws_size,
                              hipStream_t stream) {
  const float* boxes = (const float*)d_in[0];
  const float* scores = (const float*)d_in[1];
  float* out = (float*)d_out;
  (void)d_ws; (void)ws_size; (void)n_in;
  const int B = out_size / (MAXDET * 5 + 1);  // [B,100,5] + [B]
  postproc_kernel<<<B, NT, 0, stream>>>(boxes, scores, out, B);
}

// Round 13
// 23.386 us; speedup vs baseline: 1.0807x; 1.0807x over previous
//
#include <hip/hip_runtime.h>

#define NT 1024
#define NW 16        // waves per block
#define NH 4         // sub-histograms
#define NBOX 4096
#define NPT 4        // scores per thread
#define MAXDET 100
#define KSEL 192     // top-K selection target (>= 100 + NMS-suppressed margin)
#define CAP 256      // candidate capacity (4-thread rank requires C <= 256)
#define MSMALL 256   // take-all threshold (skip histogram); must be <= CAP

typedef unsigned long long u64;
typedef unsigned int u32;

__device__ __forceinline__ float iou_xyxy(float4 a, float4 c) {
  float aa = fmaxf(a.z - a.x, 0.f) * fmaxf(a.w - a.y, 0.f);
  float ca = fmaxf(c.z - c.x, 0.f) * fmaxf(c.w - c.y, 0.f);
  float w = fmaxf(fminf(a.z, c.z) - fmaxf(a.x, c.x), 0.f);
  float h = fmaxf(fminf(a.w, c.w) - fmaxf(a.y, c.y), 0.f);
  float inter = w * h;
  return inter / fmaxf(aa + ca - inter, 1e-9f);
}

__device__ __forceinline__ u64 wave_or64(u64 v) {
#pragma unroll
  for (int d = 1; d < 64; d <<= 1) v |= __shfl_xor(v, d);
  return v;
}

// Exact greedy over 64 slots: rows_mine = suppression row of element `lane`.
__device__ __forceinline__ u64 serial_greedy(u64 rows_mine, u64 removed) {
  u64 keep = 0ull;
  for (int ii = 0; ii < 64; ++ii) {
    u64 row = __shfl(rows_mine, ii);
    if (!((removed >> ii) & 1ull)) { keep |= 1ull << ii; removed |= row; }
  }
  return keep;
}

// 128-wide chunked greedy NMS over sorted (descending) keys.
// LDSBOX: boxes are pre-staged in rank order in cbst; else scattered global bx.
template <bool LDSBOX>
__device__ void run_nms128(const u64* keys, int len, const float4* __restrict__ bx,
                           const float4* cbst,
                           float4* chbox, float4* chcw, u64* srowLo, u64* srowHi,
                           u64* crossM, u64* keptkey, float4* keptxy, float4* keptcw,
                           int* p_kept, int tid) {
  const int lane = tid & 63;
  for (int base = 0; base < len; base += 128) {
    if (*p_kept >= MAXDET) break;  // uniform (written before a barrier)
    const int L = min(128, len - base);
    if (tid < 128) {  // ---- stage 128 boxes in one parallel round ----
      if (tid < 2) crossM[tid] = 0ull;
      float4 bb = make_float4(0.f, 0.f, 0.f, 0.f);
      float4 c = make_float4(0.f, 0.f, 0.f, 0.f);
      if (tid < L) {
        if (LDSBOX) {
          c = cbst[base + tid];  // contiguous: cbst is in rank order
        } else {
          u64 k = keys[base + tid];
          int orig = NBOX - 1 - (int)(k & 0xFFFFFFFFull);
          c = bx[orig];
        }
        bb = make_float4(c.x - 0.5f * c.z, c.y - 0.5f * c.w,
                         c.x + 0.5f * c.z, c.y + 0.5f * c.w);
      }
      chbox[tid] = bb;
      chcw[tid] = c;
      srowLo[tid] = 0ull;
      srowHi[tid] = 0ull;
    }
    __syncthreads();
    const int kept0 = *p_kept;
    {  // ---- pair tests: 128 rows x 8 slices ----
      int i = tid & 127, slice = tid >> 7;
      if (i < L) {
        float4 a = chbox[i];
        bool hit = false;
        for (int k0 = slice; k0 < kept0 && !hit; k0 += 8)
          if (iou_xyxy(a, keptxy[k0]) > 0.7f) hit = true;
        if (hit) atomicOr(&crossM[i >> 6], 1ull << (i & 63));
        u64 blo = 0ull, bhi = 0ull;
        for (int j = i + 1 + slice; j < L; j += 8)
          if (iou_xyxy(a, chbox[j]) > 0.7f) {
            if (j < 64) blo |= 1ull << j; else bhi |= 1ull << (j - 64);
          }
        if (blo) atomicOr(&srowLo[i], blo);
        if (bhi) atomicOr(&srowHi[i], bhi);
      }
    }
    __syncthreads();
    if (tid < 64) {  // ---- two-half greedy resolution, wave 0 ----
      u64 remL = crossM[0], remH = crossM[1];
      if (L < 64) remL |= ~((1ull << L) - 1ull);
      if (L <= 64) remH = ~0ull;
      else if (L < 128) remH |= ~((1ull << (L - 64)) - 1ull);
      u64 rAlo = srowLo[lane], rAhi = srowHi[lane];  // row of element lane
      u64 rBhi = srowHi[64 + lane];                  // row of element 64+lane
      // half 1
      u64 K1 = ~remL;
      u64 c1 = wave_or64(((K1 >> lane) & 1ull) ? (rAlo & K1) : 0ull);
      u64 keep1 = (c1 == 0ull) ? K1 : serial_greedy(rAlo, remL);
      // cross-suppression from half-1 keepers into half 2
      u64 remH2 = remH | wave_or64(((keep1 >> lane) & 1ull) ? rAhi : 0ull);
      // half 2
      u64 K2 = ~remH2;
      u64 c2 = wave_or64(((K2 >> lane) & 1ull) ? (rBhi & K2) : 0ull);
      u64 keep2 = (c2 == 0ull) ? K2 : serial_greedy(rBhi, remH2);
      // append
      int cnt1 = (int)__popcll(keep1);
      u64 below = (1ull << lane) - 1ull;
      if ((keep1 >> lane) & 1ull) {
        int pos = kept0 + (int)__popcll(keep1 & below);
        if (pos < MAXDET) {
          keptkey[pos] = keys[base + lane];
          keptxy[pos] = chbox[lane];
          keptcw[pos] = chcw[lane];
        }
      }
      if ((keep2 >> lane) & 1ull) {
        int pos = kept0 + cnt1 + (int)__popcll(keep2 & below);
        if (pos < MAXDET) {
          keptkey[pos] = keys[base + 64 + lane];
          keptxy[pos] = chbox[64 + lane];
          keptcw[pos] = chcw[64 + lane];
        }
      }
      if (lane == 0)
        *p_kept = min(MAXDET, kept0 + cnt1 + (int)__popcll(keep2));
    }
    __syncthreads();
  }
}

__global__ __launch_bounds__(NT) void postproc_kernel(
    const float* __restrict__ boxes,   // [B, NBOX, 4] cxcywh
    const float* __restrict__ scores,  // [B, NBOX]
    float* __restrict__ out,           // [B*MAXDET*5] packed, then [B] num
    int B) {
  const int b = blockIdx.x;
  const int tid = threadIdx.x, wid = tid >> 6, lane = tid & 63;

  __shared__ u32 hist[NH][256];    // 4KB sub-histograms (zeroed at entry)
  __shared__ u64 cand[CAP];        // compaction order
  __shared__ u64 sortedCand[CAP];  // rank order (descending)
  __shared__ float4 cbst[CAP];     // rank order -> cxcywh box
  __shared__ u64 skey[NBOX];       // 32KB, fallback full sort only
  __shared__ float4 chbox[128];    // chunk xyxy
  __shared__ float4 chcw[128];     // chunk cxcywh
  __shared__ u64 srowLo[128], srowHi[128];
  __shared__ u64 crossM[2];
  __shared__ float4 keptxy[MAXDET];
  __shared__ float4 keptcw[MAXDET];
  __shared__ u64 keptkey[MAXDET];
  __shared__ int s_M, s_C, s_kept, s_ovf, s_byte, s_above, s_bcnt;
  __shared__ int s_minP, s_maxP;

  const float* sc = scores + (size_t)b * NBOX;
  const float4* bx = (const float4*)boxes + (size_t)b * NBOX;

  if (tid == 0) {
    s_M = 0; s_C = 0; s_kept = 0; s_ovf = 0;
    s_byte = 0; s_above = 0; s_bcnt = -1;
    s_minP = 0x7FFFFFFF; s_maxP = -1;
  }
  ((u32*)hist)[tid] = 0u;  // NT == NH*256: full zero, hidden under Phase 1

  // ---- Phase 1: one float4 of scores/thread; keys in regs; M + exp range ----
  u64 key[NPT];
  {
    const int t4 = tid * NPT;
    float4 f0 = *(const float4*)(sc + t4);
    float xs[NPT] = {f0.x, f0.y, f0.z, f0.w};
    int myM = 0, pmin = 0x7FFFFFFF, pmax = -1;
#pragma unroll
    for (int q = 0; q < NPT; ++q) {
      float x = xs[q];
      bool valid = (x > 0.5f);
      u32 bits = __float_as_uint(x);
      key[q] = valid ? (((u64)bits << 32) | (u64)(u32)(NBOX - 1 - (t4 + q))) : 0ull;
      if (valid) {
        int p = (int)(bits >> 23);
        pmin = min(pmin, p); pmax = max(pmax, p); ++myM;
      }
    }
#pragma unroll
    for (int d = 1; d < 64; d <<= 1) {
      myM += __shfl_xor(myM, d);
      pmin = min(pmin, __shfl_xor(pmin, d));
      pmax = max(pmax, __shfl_xor(pmax, d));
    }
    __syncthreads();  // s_* init + hist zero visible
    if (lane == 0) {
      atomicAdd(&s_M, myM);
      atomicMin(&s_minP, pmin);
      atomicMax(&s_maxP, pmax);
    }
  }
  __syncthreads();
  const int M = s_M;
  const bool uniformP = (s_minP == s_maxP);  // all valid share sign+exponent
  bool fullpath = false;
  bool usehist = false;
  u32 thr = 0;

  // ---- Phase 2: selection threshold (1-pass mantissa histogram, 2 barriers) ----
  if (M > MSMALL) {
    if (uniformP) {
      usehist = true;
#pragma unroll
      for (int q = 0; q < NPT; ++q)
        if (key[q]) atomicAdd(&hist[wid >> 2][(u32)(key[q] >> 47) & 255u], 1u);
      __syncthreads();
      if (tid < 64) {  // wave 0: merge sub-hists inline + suffix scan (4 bins/lane)
        int cc[4];
#pragma unroll
        for (int qq = 0; qq < 4; ++qq) {
          int bin = tid * 4 + qq;
          cc[qq] = (int)(hist[0][bin] + hist[1][bin] + hist[2][bin] + hist[3][bin]);
        }
        int tot = cc[0] + cc[1] + cc[2] + cc[3];
        int suf = tot;
#pragma unroll
        for (int d = 1; d < 64; d <<= 1) {
          int o = __shfl_down(suf, d);
          if (tid + d < 64) suf += o;
        }
        if (suf - tot < KSEL && suf >= KSEL) {  // unique crossing lane
          int cum = suf - tot;
          for (int qq = 3; qq >= 0; --qq) {
            if (cum + cc[qq] >= KSEL) { s_byte = tid * 4 + qq; s_above = cum; s_bcnt = cc[qq]; break; }
            cum += cc[qq];
          }
        }
      }
      __syncthreads();
      thr = (u32)s_byte;
      // exact candidate count = s_above + s_bcnt; must fit CAP for the 4-thread rank
      if (s_bcnt < 0 || s_above + s_bcnt > CAP) fullpath = true;
    } else {
      fullpath = true;
    }
  }

  // ---- Phase 3: compact candidates (wave-aggregated atomics) ----
  if (!fullpath) {
#pragma unroll
    for (int q = 0; q < NPT; ++q) {
      bool take = key[q] && (!usehist || (((u32)(key[q] >> 47) & 255u) >= thr));
      u64 bal = __ballot(take);
      if (bal) {
        int leader = __ffsll((unsigned long long)bal) - 1;
        int basep = 0;
        if (lane == leader) basep = atomicAdd(&s_C, (int)__popcll(bal));
        basep = __shfl(basep, leader);
        if (take) {
          int pos = basep + (int)__popcll(bal & ((1ull << lane) - 1ull));
          if (pos < CAP) cand[pos] = key[q];
          else s_ovf = 1;
        }
      }
    }
  }
  __syncthreads();
  const int C = min(s_C, CAP);
  if (s_ovf) fullpath = true;

  // ---- Phase 4: gather+rank (4 threads/cand; gather thread == writer) + NMS ----
  if (!fullpath && C > 0) {
    const int i = tid >> 2, sl = tid & 3;
    u64 ki = 0ull;
    float4 gbox;
    const bool own = (sl == 0) && (i < C);
    if (i < C) ki = cand[i];  // LDS broadcast across the quad
    if (own) {                // issue scattered gather early; hides under rank
      int orig = NBOX - 1 - (int)(ki & 0xFFFFFFFFull);
      gbox = bx[orig];
    }
    int cnt = 0;
    if (i < C)
      for (int j = sl; j < C; j += 4) cnt += (cand[j] > ki) ? 1 : 0;
    cnt += __shfl_xor(cnt, 1);  // quad lanes share the same candidate
    cnt += __shfl_xor(cnt, 2);
    if (own) { sortedCand[cnt] = ki; cbst[cnt] = gbox; }  // boxes in rank order
    __syncthreads();
    run_nms128<true>(sortedCand, C, bx, cbst, chbox, chcw,
                     srowLo, srowHi, crossM, keptkey, keptxy, keptcw, &s_kept, tid);
  }

  // ---- Phase 5: fully-general fallback (pathological inputs only) ----
  const int kept1 = s_kept;
  const bool need_full = fullpath || (kept1 < MAXDET && usehist && C < M);
  __syncthreads();
  if (need_full) {
    if (tid == 0) s_kept = 0;
#pragma unroll
    for (int q = 0; q < NPT; ++q) {
      int n = tid * NPT + q;
      skey[n] = key[q] ? key[q] : (u64)(u32)(NBOX - 1 - n);
    }
    __syncthreads();
    for (int k = 2; k <= NBOX; k <<= 1)
      for (int j = k >> 1; j > 0; j >>= 1) {
#pragma clang loop unroll(disable)
        for (int t = tid; t < NBOX; t += NT) {
          int ixj = t ^ j;
          if (ixj > t) {
            u64 a = skey[t], c2 = skey[ixj];
            bool up = (t & k) != 0;
            if (up ? (a > c2) : (a < c2)) { skey[t] = c2; skey[ixj] = a; }
          }
        }
        __syncthreads();
      }
    run_nms128<false>(skey, M, bx, cbst, chbox, chcw,
                      srowLo, srowHi, crossM, keptkey, keptxy, keptcw, &s_kept, tid);
  }

  // ---- Phase 6: outputs (all from LDS; coalesced stores) ----
  const int nk = s_kept;
  if (tid < MAXDET) {
    float v0 = 0.f, v1 = 0.f, v2 = 0.f, v3 = 0.f, v4 = 0.f;
    if (tid < nk) {
      float4 bb = keptcw[tid];  // original cxcywh (staged during NMS)
      v0 = bb.x; v1 = bb.y; v2 = bb.z; v3 = bb.w;
      v4 = __uint_as_float((u32)(keptkey[tid] >> 32));
    }
    float* o = out + ((size_t)b * MAXDET + tid) * 5;
    o[0] = v0; o[1] = v1; o[2] = v2; o[3] = v3; o[4] = v4;
  }
  if (tid == 0) out[(size_t)B * MAXDET * 5 + b] = (float)nk;
}

extern "C" void kernel_launch(void* const* d_in, const int* in_sizes, int n_in,
                              void* d_out, int out_size, void* d_ws, size_t ws_size,
                              hipStream_t stream) {
  const float* boxes = (const float*)d_in[0];
  const float* scores = (const float*)d_in[1];
  float* out = (float*)d_out;
  (void)d_ws; (void)ws_size; (void)n_in;
  const int B = out_size / (MAXDET * 5 + 1);  // [B,100,5] + [B]
  postproc_kernel<<<B, NT, 0, stream>>>(boxes, scores, out, B);
}